// Round 4
// baseline (274.788 us; speedup 1.0000x reference)
//
#include <hip/hip_runtime.h>
#include <math.h>

// Problem constants: B=32, H=1024, W=1024, N=100000
#define RD_H 1024
#define RD_W 1024
#define RD_N 100000
#define HW   (RD_H * RD_W)          // 1,048,576 floats = 4 MB per image
#define LINES_PER_IMG 65536         // 4 MB / 64 B
#define BDIM 256
#define UNROLL 8                    // points per thread per phase
#define NXCD 8
#define IMGS_PER_XCD 4              // 32 images / 8 XCDs
#define BPX 49                      // blocks per XCD (49*2048 >= 100000)
#define PPB (BDIM * UNROLL)         // 2048 points per block-phase
#define LPB ((LINES_PER_IMG + BPX - 1) / BPX)   // 1338 prefetch lines per block

typedef int vint4 __attribute__((ext_vector_type(4)));

__global__ void rd_zero_kernel(float* out) { out[0] = 0.0f; }

__global__ __launch_bounds__(BDIM) void rd_loss_kernel(
    const float* __restrict__ depth,   // (B, H, W) fp32
    const int*   __restrict__ xA,
    const int*   __restrict__ yA,
    const int*   __restrict__ xB,
    const int*   __restrict__ yB,
    const int*   __restrict__ ord,
    float* __restrict__ out, float inv_total)
{
    // blockIdx % 8 -> XCD (round-robin dispatch). Each XCD owns 4 images and
    // processes them one at a time: 4 MB image == 4 MB XCD L2.
    int xcd = blockIdx.x % NXCD;
    int k   = blockIdx.x / NXCD;       // [0, BPX)
    int tid = threadIdx.x;

    float loss = 0.0f;
    unsigned pf = 0u;                  // keeps prefetch loads alive

    for (int r = 0; r < IMGS_PER_XCD; ++r) {
        int b = xcd * IMGS_PER_XCD + r;
        const float* img = depth + (size_t)b * HW;

        // --- Coalesced L2 prefetch of this block's 1/49th of image b ---
        // One 4 B touch per 64 B line; wave touches 64 consecutive lines
        // (4 KB sequential region) -> DRAM-page-friendly streaming, no
        // random-miss MSHR latency product.
        {
            int line0 = k * LPB;
            int line_end = line0 + LPB;
            if (line_end > LINES_PER_IMG) line_end = LINES_PER_IMG;
            for (int l = line0 + tid; l < line_end; l += BDIM)
                pf += __float_as_uint(img[l * 16]);
        }

        // --- This phase's points (all in image b) ---
        int i0 = b * RD_N + k * PPB + tid * UNROLL;
        if (i0 + UNROLL <= (b + 1) * RD_N) {
            // Streaming (nontemporal) index loads: don't evict the image from L2.
            vint4 xa0 = __builtin_nontemporal_load((const vint4*)(xA + i0));
            vint4 xa1 = __builtin_nontemporal_load((const vint4*)(xA + i0 + 4));
            vint4 ya0 = __builtin_nontemporal_load((const vint4*)(yA + i0));
            vint4 ya1 = __builtin_nontemporal_load((const vint4*)(yA + i0 + 4));
            vint4 xb0 = __builtin_nontemporal_load((const vint4*)(xB + i0));
            vint4 xb1 = __builtin_nontemporal_load((const vint4*)(xB + i0 + 4));
            vint4 yb0 = __builtin_nontemporal_load((const vint4*)(yB + i0));
            vint4 yb1 = __builtin_nontemporal_load((const vint4*)(yB + i0 + 4));
            vint4 od0 = __builtin_nontemporal_load((const vint4*)(ord + i0));
            vint4 od1 = __builtin_nontemporal_load((const vint4*)(ord + i0 + 4));

            int xav[UNROLL], yav[UNROLL], xbv[UNROLL], ybv[UNROLL], odv[UNROLL];
            #pragma unroll
            for (int j = 0; j < 4; ++j) {
                xav[j] = xa0[j]; xav[j + 4] = xa1[j];
                yav[j] = ya0[j]; yav[j + 4] = ya1[j];
                xbv[j] = xb0[j]; xbv[j + 4] = xb1[j];
                ybv[j] = yb0[j]; ybv[j + 4] = yb1[j];
                odv[j] = od0[j]; odv[j + 4] = od1[j];
            }

            // Issue all 16 gathers (L2-resident image) before any use.
            float za[UNROLL], zb[UNROLL];
            #pragma unroll
            for (int j = 0; j < UNROLL; ++j)
                za[j] = img[yav[j] * RD_W + xav[j]];
            #pragma unroll
            for (int j = 0; j < UNROLL; ++j)
                zb[j] = img[ybv[j] * RD_W + xbv[j]];

            #pragma unroll
            for (int j = 0; j < UNROLL; ++j) {
                float diff = za[j] - zb[j];
                float gt   = (float)(odv[j] - 1);   // {-1, 0, 1}
                float mask = fabsf(gt);             // {0, 1}
                // stable softplus(-gt*diff) = max(x,0) + log1p(exp(-|x|))
                float x  = -gt * diff;
                float sp = fmaxf(x, 0.0f) + log1pf(__expf(-fabsf(x)));
                loss += mask * sp + (1.0f - mask) * diff * diff;
            }
        }
    }

    // Keep prefetch loads from being dead-code-eliminated (never true in practice;
    // even if it fired, +1e-30 is invisible vs the 2.5e-2 threshold).
    if (pf == 0x9E3779B9u) loss += 1e-30f;

    // wave-64 shuffle reduction
    #pragma unroll
    for (int off = 32; off > 0; off >>= 1)
        loss += __shfl_down(loss, off, 64);

    __shared__ float wsum[BDIM / 64];
    int lane = threadIdx.x & 63;
    int wid  = threadIdx.x >> 6;
    if (lane == 0) wsum[wid] = loss;
    __syncthreads();

    if (threadIdx.x == 0) {
        float s = 0.0f;
        #pragma unroll
        for (int w = 0; w < BDIM / 64; ++w) s += wsum[w];
        atomicAdd(out, s * inv_total);
    }
}

extern "C" void kernel_launch(void* const* d_in, const int* in_sizes, int n_in,
                              void* d_out, int out_size, void* d_ws, size_t ws_size,
                              hipStream_t stream) {
    const float* depth = (const float*)d_in[0];
    const int*   xA    = (const int*)d_in[1];
    const int*   yA    = (const int*)d_in[2];
    const int*   xB    = (const int*)d_in[3];
    const int*   yB    = (const int*)d_in[4];
    const int*   ord   = (const int*)d_in[5];
    float* out = (float*)d_out;

    int total = in_sizes[1];                 // 3,200,000
    float inv_total = 1.0f / (float)total;

    // d_out is poisoned to 0xAA before every timed launch — zero it first.
    rd_zero_kernel<<<1, 1, 0, stream>>>(out);

    rd_loss_kernel<<<NXCD * BPX, BDIM, 0, stream>>>(   // 392 blocks, all co-resident
        depth, xA, yA, xB, yB, ord, out, inv_total);
}

// Round 5
// 274.346 us; speedup vs baseline: 1.0016x; 1.0016x over previous
//
#include <hip/hip_runtime.h>
#include <math.h>

// Problem constants: B=32, H=1024, W=1024, N=100000
#define RD_H 1024
#define RD_W 1024
#define RD_N 100000
#define HW   (RD_H * RD_W)
#define BDIM 256
#define UNROLL 2          // small quanta -> sliding co-residency window ~1.3 img/XCD
#define NXCD 8
#define KPB  782          // blocks per XCD slice; 8*782 = 6256 >= 6250 needed

typedef int vint2 __attribute__((ext_vector_type(2)));

__global__ void rd_zero_kernel(float* out) { out[0] = 0.0f; }

__global__ __launch_bounds__(BDIM, 8) void rd_loss_kernel(
    const float* __restrict__ depth,   // (B, H, W) fp32
    const int*   __restrict__ xA,
    const int*   __restrict__ yA,
    const int*   __restrict__ xB,
    const int*   __restrict__ yB,
    const int*   __restrict__ ord,
    float* __restrict__ out,
    int total, float inv_total)
{
    // XCD-locality swizzle: blockIdx%8 -> XCD; XCD x walks consecutive point
    // ranges in dispatch order. Small quanta (512 pts/block) + in-order block
    // replacement => co-resident window per XCD ~1.3 images, near-L2-resident.
    int v  = (blockIdx.x % NXCD) * KPB + (blockIdx.x / NXCD);
    int i0 = (v * BDIM + threadIdx.x) * UNROLL;

    float loss = 0.0f;
    if (i0 < total) {
        // Pair [i0, i0+1] never crosses an image boundary (boundaries even).
        int b = i0 / RD_N;
        const float* img = depth + (size_t)b * HW;

        // Nontemporal index loads: stream, don't evict the image from L2.
        vint2 xa = __builtin_nontemporal_load((const vint2*)(xA + i0));
        vint2 ya = __builtin_nontemporal_load((const vint2*)(yA + i0));
        vint2 xb = __builtin_nontemporal_load((const vint2*)(xB + i0));
        vint2 yb = __builtin_nontemporal_load((const vint2*)(yB + i0));
        vint2 od = __builtin_nontemporal_load((const vint2*)(ord + i0));

        // Issue all 4 gathers before any use.
        float za0 = img[ya[0] * RD_W + xa[0]];
        float za1 = img[ya[1] * RD_W + xa[1]];
        float zb0 = img[yb[0] * RD_W + xb[0]];
        float zb1 = img[yb[1] * RD_W + xb[1]];

        {
            float diff = za0 - zb0;
            float gt   = (float)(od[0] - 1);
            float mask = fabsf(gt);
            float x    = -gt * diff;
            float sp   = fmaxf(x, 0.0f) + log1pf(__expf(-fabsf(x)));
            loss += mask * sp + (1.0f - mask) * diff * diff;
        }
        {
            float diff = za1 - zb1;
            float gt   = (float)(od[1] - 1);
            float mask = fabsf(gt);
            float x    = -gt * diff;
            float sp   = fmaxf(x, 0.0f) + log1pf(__expf(-fabsf(x)));
            loss += mask * sp + (1.0f - mask) * diff * diff;
        }
    }

    // wave-64 shuffle reduction
    #pragma unroll
    for (int off = 32; off > 0; off >>= 1)
        loss += __shfl_down(loss, off, 64);

    __shared__ float wsum[BDIM / 64];
    int lane = threadIdx.x & 63;
    int wid  = threadIdx.x >> 6;
    if (lane == 0) wsum[wid] = loss;
    __syncthreads();

    if (threadIdx.x == 0) {
        float s = 0.0f;
        #pragma unroll
        for (int w = 0; w < BDIM / 64; ++w) s += wsum[w];
        atomicAdd(out, s * inv_total);   // pre-scaled partial: sum stays O(1)
    }
}

extern "C" void kernel_launch(void* const* d_in, const int* in_sizes, int n_in,
                              void* d_out, int out_size, void* d_ws, size_t ws_size,
                              hipStream_t stream) {
    const float* depth = (const float*)d_in[0];
    const int*   xA    = (const int*)d_in[1];
    const int*   yA    = (const int*)d_in[2];
    const int*   xB    = (const int*)d_in[3];
    const int*   yB    = (const int*)d_in[4];
    const int*   ord   = (const int*)d_in[5];
    float* out = (float*)d_out;

    int total = in_sizes[1];                 // 3,200,000 (divisible by 512)
    float inv_total = 1.0f / (float)total;

    // d_out is poisoned to 0xAA before every timed launch — zero it first.
    rd_zero_kernel<<<1, 1, 0, stream>>>(out);

    rd_loss_kernel<<<NXCD * KPB, BDIM, 0, stream>>>(   // 6256 blocks
        depth, xA, yA, xB, yB, ord, out, total, inv_total);
}